// Round 8
// baseline (286.574 us; speedup 1.0000x reference)
//
#include <hip/hip_runtime.h>

#define DEVFN __device__ __forceinline__

static constexpr int B = 64, U = 4096, H = 64;
static constexpr int N = B * U;       // 262144 total sequential steps
static constexpr int CHUNK = 128;     // output rows per chunk
static constexpr int LBURN = 128;     // speculative burn-in steps
static constexpr int C = N / CHUNK;   // 2048 chunks -> 2 waves/SIMD

// x' staging buffer as a device global: no aliasing with d_out, no dependence
// on workspace size, no hipMalloc. +8 rows padding so the 4-deep prefetch of
// the last chunk never reads out of bounds.
__device__ __align__(16) float g_xbuf[(N + 8) * H];

// permlane swap builtins return: unsigned int vector of 2 (index with [0]/[1])
typedef unsigned int v2u __attribute__((__vector_size__(2 * sizeof(unsigned int))));

// ============================================================================
// Kernel 1: parallel input projection.
// R12: w[64] loads pinned via zero-cost asm ("+v") so machine-sinking cannot
// push the loop-invariant loads back into the loop (W_ih is restrict-const,
// so sinking is LEGAL and the backend did it whenever occupancy targets got
// tight — the R9-R11 lesson from scan, VGPR 84 -> 40).
// ============================================================================
__global__ __launch_bounds__(64, 1) void proj_kernel(
    const int*   __restrict__ y,      // [B][U]
    const float* __restrict__ emb,    // [V][H]
    const float* __restrict__ W_ih,   // [H][H]
    const float* __restrict__ b_ih,
    const float* __restrict__ b_hh)
{
    __shared__ __align__(16) float e_s[64][H];
    __shared__ int ids_s[64];
    const int l    = threadIdx.x;          // 0..63
    const int row0 = blockIdx.x * 64;

    float w[H];
    #pragma unroll
    for (int k4 = 0; k4 < 16; ++k4) {
        float4 v = *(const float4*)&W_ih[l * H + k4 * 4];
        w[k4*4+0] = v.x; w[k4*4+1] = v.y; w[k4*4+2] = v.z; w[k4*4+3] = v.w;
    }
    #pragma unroll
    for (int k = 0; k < H; ++k) { asm("" : "+v"(w[k])); }   // pin resident
    const float bias = b_ih[l] + b_hh[l];

    {
        int i = row0 + l;
        ids_s[l] = y[(i & (B - 1)) * U + (i >> 6)];   // (u = i/B, b = i%B)
    }
    __syncthreads();

    #pragma unroll 4
    for (int r = 0; r < 64; ++r) {
        e_s[r][l] = emb[ids_s[r] * H + l];
    }
    __syncthreads();

    #pragma unroll 1
    for (int r = 0; r < 64; ++r) {
        float acc0 = bias, acc1 = 0.f;
        #pragma unroll
        for (int k4 = 0; k4 < 16; ++k4) {
            float4 ev = *(const float4*)&e_s[r][k4 * 4];
            acc0 = fmaf(ev.x, w[k4*4+0], acc0);
            acc1 = fmaf(ev.y, w[k4*4+1], acc1);
            acc0 = fmaf(ev.z, w[k4*4+2], acc0);
            acc1 = fmaf(ev.w, w[k4*4+3], acc1);
        }
        g_xbuf[(row0 + r) * H + l] = acc0 + acc1;
    }
}

// ============================================================================
// Kernel 2 (R12): speculative chunk-parallel scan — weight residency FORCED.
// R11 falsified the launch_bounds(64,2) fix: VGPR stayed 40, time identical.
// Experiment matrix across rounds: (64,1)->VGPR 84 resident (R6);
// (64)/(64,2)->VGPR 40, weights re-loaded every step (R9-R11). The backend
// legally sinks the restrict-const W_hh loads into the loop when its
// occupancy target is >1 wave/EU. Fix both ways:
//   1. __launch_bounds__(64,1): the proven-resident config. HW occupancy is
//      unaffected (alloc ~90 -> 128-granule -> 4 waves/SIMD possible; grid
//      supplies 2/SIMD).
//   2. asm("" : "+v"(w)) pin on each weight: an asm output is not a
//      sinkable/rematerializable load -> must stay live in a VGPR,
//      independent of heuristics.
// Geometry unchanged (CHUNK=128, LBURN=128). Step = R6's verified DPP matvec.
// ============================================================================

// ---- 64 named weights: wB_R = W_hh[l][16*B + ((l - R) & 15)] ----
#define DW(Bk, R) float w##Bk##_##R = W_hh[l * H + (Bk) * 16 + (((l & 15) - (R)) & 15)];
#define DWBLK(Bk) DW(Bk,0) DW(Bk,1) DW(Bk,2) DW(Bk,3) DW(Bk,4) DW(Bk,5) DW(Bk,6) DW(Bk,7) \
                  DW(Bk,8) DW(Bk,9) DW(Bk,10) DW(Bk,11) DW(Bk,12) DW(Bk,13) DW(Bk,14) DW(Bk,15)
// ---- pin: forbid sinking/remat of the weight loads (zero instructions) ----
#define PW(Bk, R) asm("" : "+v"(w##Bk##_##R));
#define PWBLK(Bk) PW(Bk,0) PW(Bk,1) PW(Bk,2) PW(Bk,3) PW(Bk,4) PW(Bk,5) PW(Bk,6) PW(Bk,7) \
                  PW(Bk,8) PW(Bk,9) PW(Bk,10) PW(Bk,11) PW(Bk,12) PW(Bk,13) PW(Bk,14) PW(Bk,15)

// ---- broadcast h -> 4 block-replicated registers (VALU-only) ----
// hbB[l] = h[16*B + (l & 15)]  (verified layout from R6..R10 passing runs)
#define BCAST(h)                                                                     \
    const unsigned hbits = (unsigned)__float_as_int(h);                              \
    v2u p  = __builtin_amdgcn_permlane32_swap(hbits, hbits, false, false);           \
    v2u q0 = __builtin_amdgcn_permlane16_swap(p[0], p[0], false, false);             \
    v2u q1 = __builtin_amdgcn_permlane16_swap(p[1], p[1], false, false);             \
    float hb0 = __int_as_float((int)q0[0]), hb1 = __int_as_float((int)q0[1]);        \
    float hb2 = __int_as_float((int)q1[0]), hb3 = __int_as_float((int)q1[1]);

// ---- fused DPP MAC: acc += rotate16(hb, R) * w ----
#define FMAC_DPP(ACC, HB, W, R)                                              \
    asm("v_fmac_f32_dpp %0, %1, %2 row_ror:" #R " row_mask:0xf bank_mask:0xf"\
        : "+v"(ACC) : "v"(HB), "v"(W))
// ---- chain entry: dst = rotate16(hb, R) * w; AFTER = ordering-only dep ----
#define FMUL_DPP_ORD(DST, HB, W, R, AFTER)                                   \
    asm("v_mul_f32_dpp %0, %1, %2 row_ror:" #R " row_mask:0xf bank_mask:0xf" \
        : "=v"(DST) : "v"(HB), "v"(W), "v"(AFTER))

#define FRA(R) FMAC_DPP(a0, hb0, w0_##R, R); FMAC_DPP(a1, hb1, w1_##R, R);   \
               FMAC_DPP(a2, hb2, w2_##R, R); FMAC_DPP(a3, hb3, w3_##R, R);
#define FRB(R) FMAC_DPP(b0, hb0, w0_##R, R); FMAC_DPP(b1, hb1, w1_##R, R);   \
               FMAC_DPP(b2, hb2, w2_##R, R); FMAC_DPP(b3, hb3, w3_##R, R);

// ---- one recurrence step: h = tanh(XV + W*h); optional store ----
// Plain R=0 MACs provide the >=2-instr spacing between the permlane writes
// of hb* and the first inline-asm DPP reads (DPP RAW hazard).
#define STEP(XV, ST) {                                                       \
    BCAST(h)                                                                 \
    float a0 = fmaf(hb0, w0_0, (XV));                                        \
    float a1 = hb1 * w1_0;                                                   \
    float a2 = hb2 * w2_0;                                                   \
    float a3 = hb3 * w3_0;                                                   \
    float b0, b1, b2, b3;                                                    \
    FMUL_DPP_ORD(b0, hb0, w0_8, 8, a0);                                      \
    FMUL_DPP_ORD(b1, hb1, w1_8, 8, a1);                                      \
    FMUL_DPP_ORD(b2, hb2, w2_8, 8, a2);                                      \
    FMUL_DPP_ORD(b3, hb3, w3_8, 8, a3);                                      \
    FRA(1)  FRB(9)  FRA(2)  FRB(10) FRA(3)  FRB(11) FRA(4)  FRB(12)          \
    FRA(5)  FRB(13) FRA(6)  FRB(14) FRA(7)  FRB(15)                          \
    float z  = ((a0 + b0) + (a1 + b1)) + ((a2 + b2) + (a3 + b3));            \
    float t_ = __builtin_amdgcn_exp2f(z * 2.8853900817779268f);              \
    h = fmaf(-2.0f, __builtin_amdgcn_rcpf(1.0f + t_), 1.0f);                 \
    ST                                                                       \
}

__global__ __launch_bounds__(64, 1) void scan_spec_kernel(
    const float* __restrict__ W_hh,   // [H][H]
    const float* __restrict__ h0,     // [H]
    float*       __restrict__ xout)   // [N][H]  (final output)
{
    const int c = blockIdx.x;         // chunk id, 0..C-1
    const int l = threadIdx.x;        // lane = output index j

    DWBLK(0) DWBLK(1) DWBLK(2) DWBLK(3)   // 64 scalar weights -> VGPRs
    PWBLK(0) PWBLK(1) PWBLK(2) PWBLK(3)   // pin them there (0 instructions)

    const int srow = c * CHUNK;                       // first output row
    const int s0   = (srow > LBURN) ? (srow - LBURN) : 0;   // sim start row
    const int nburn = srow - s0;                      // 0 or LBURN

    // exact start (h0) when the window reaches row 0; else speculative h=0
    float h = (s0 == 0) ? h0[l] : 0.0f;

    const float* xp = g_xbuf + (size_t)s0 * H + l;
    float*       op = xout   + (size_t)srow * H + l;

    // 4-deep x prefetch ring
    float x0 = xp[0*H], x1 = xp[1*H], x2 = xp[2*H], x3 = xp[3*H];
    xp += 4 * H;

    // ---- burn-in: no stores (nburn is a multiple of 4) ----
    #pragma unroll 1
    for (int i = 0; i < nburn; i += 4) {
        STEP(x0, ) x0 = xp[0*H];
        STEP(x1, ) x1 = xp[1*H];
        STEP(x2, ) x2 = xp[2*H];
        STEP(x3, ) x3 = xp[3*H];
        xp += 4 * H;
    }

    // ---- output phase: CHUNK rows, store h each step ----
    // (prefetch overruns by <=4 rows into the padded tail of g_xbuf)
    #pragma unroll 1
    for (int i = 0; i < CHUNK; i += 4) {
        STEP(x0, op[0*H] = h;) x0 = xp[0*H];
        STEP(x1, op[1*H] = h;) x1 = xp[1*H];
        STEP(x2, op[2*H] = h;) x2 = xp[2*H];
        STEP(x3, op[3*H] = h;) x3 = xp[3*H];
        xp += 4 * H;
        op += 4 * H;
    }
}

// ============================================================================
extern "C" void kernel_launch(void* const* d_in, const int* in_sizes, int n_in,
                              void* d_out, int out_size, void* d_ws, size_t ws_size,
                              hipStream_t stream) {
    const int*   y    = (const int*)  d_in[0];
    const float* emb  = (const float*)d_in[1];
    const float* W_ih = (const float*)d_in[2];
    const float* W_hh = (const float*)d_in[3];
    const float* b_ih = (const float*)d_in[4];
    const float* b_hh = (const float*)d_in[5];
    const float* h0   = (const float*)d_in[6];
    float* out = (float*)d_out;

    proj_kernel<<<dim3(N / 64), dim3(64), 0, stream>>>(y, emb, W_ih, b_ih, b_hh);
    scan_spec_kernel<<<dim3(C), dim3(64), 0, stream>>>(W_hh, h0, out);
}